// Round 1
// baseline (422.248 us; speedup 1.0000x reference)
//
#include <hip/hip_runtime.h>
#include <cmath>

// ---------------- CSR build ----------------

__global__ __launch_bounds__(256) void k_count(const int* __restrict__ dst, int* __restrict__ cnt, int E) {
  int e = blockIdx.x * 256 + threadIdx.x;
  if (e < E) atomicAdd(&cnt[dst[e]], 1);
}

__global__ __launch_bounds__(256) void k_dinv(const int* __restrict__ cnt, float* __restrict__ dinv, int n) {
  int i = blockIdx.x * 256 + threadIdx.x;
  if (i < n) dinv[i] = rsqrtf((float)(cnt[i] + 1));  // +1 = self loop
}

__global__ __launch_bounds__(256) void k_chunk_sum(const int* __restrict__ cnt, int* __restrict__ bsum, int n) {
  __shared__ int s[256];
  int i = blockIdx.x * 256 + threadIdx.x;
  s[threadIdx.x] = (i < n) ? cnt[i] : 0;
  __syncthreads();
  for (int off = 128; off > 0; off >>= 1) {
    if (threadIdx.x < off) s[threadIdx.x] += s[threadIdx.x + off];
    __syncthreads();
  }
  if (threadIdx.x == 0) bsum[blockIdx.x] = s[0];
}

__global__ __launch_bounds__(256) void k_scan_bsum(int* __restrict__ bsum, int nb) {
  __shared__ int s[256];
  int t = threadIdx.x;
  int v = (t < nb) ? bsum[t] : 0;
  s[t] = v;
  __syncthreads();
  for (int off = 1; off < 256; off <<= 1) {
    int u = (t >= off) ? s[t - off] : 0;
    __syncthreads();
    s[t] += u;
    __syncthreads();
  }
  if (t < nb) bsum[t] = s[t] - v;  // exclusive
}

__global__ __launch_bounds__(256) void k_scan_final(const int* __restrict__ cnt, const int* __restrict__ boff,
                                                    int* __restrict__ rp, int n) {
  __shared__ int s[256];
  int t = threadIdx.x;
  int i = blockIdx.x * 256 + t;
  int v = (i < n) ? cnt[i] : 0;
  s[t] = v;
  __syncthreads();
  for (int off = 1; off < 256; off <<= 1) {
    int u = (t >= off) ? s[t - off] : 0;
    __syncthreads();
    s[t] += u;
    __syncthreads();
  }
  int excl = s[t] - v + boff[blockIdx.x];
  if (i < n) rp[i] = excl;
  if (i == n - 1) rp[n] = excl + v;
}

__global__ __launch_bounds__(256) void k_scatter(const int* __restrict__ src, const int* __restrict__ dst,
                                                 const int* __restrict__ rp, int* __restrict__ cursor,
                                                 int* __restrict__ csr, int E) {
  int e = blockIdx.x * 256 + threadIdx.x;
  if (e < E) {
    int d = dst[e];
    int p = rp[d] + atomicAdd(&cursor[d], 1);
    csr[p] = src[e];
  }
}

// ---------------- GEMM with fused dinv row-scale ----------------
// G[i][:] = dinv[i] * (X[i][:] @ W)   X:[n][128], W:[128][M] row-major, G:[n][M]
template <int M, int MP, int ROWS>
__global__ __launch_bounds__(256) void k_gemm_dinv(const float* __restrict__ X, const float* __restrict__ W,
                                                   const float* __restrict__ dinv, float* __restrict__ G, int n) {
  constexpr int CG = MP / 4;    // col groups of 4
  constexpr int RG = 256 / CG;  // row groups of 4
  static_assert(ROWS == RG * 4, "geometry");
  __shared__ float ws[128 * MP];
  __shared__ float xs[ROWS * 128];
  int tid = threadIdx.x;
  if constexpr (M == MP) {
    for (int idx = tid * 4; idx < 128 * M; idx += 1024)
      *(float4*)&ws[idx] = *(const float4*)&W[idx];
  } else {
    for (int idx = tid; idx < 128 * MP; idx += 256) {
      int k = idx / MP, j = idx - k * MP;
      ws[idx] = (j < M) ? W[k * M + j] : 0.f;
    }
  }
  int rowBase = blockIdx.x * ROWS;
  for (int idx = tid * 4; idx < ROWS * 128; idx += 1024) {
    int r = idx >> 7;
    int gr = rowBase + r;
    float4 v = make_float4(0.f, 0.f, 0.f, 0.f);
    if (gr < n) v = *(const float4*)&X[(size_t)gr * 128 + (idx & 127)];
    *(float4*)&xs[idx] = v;
  }
  __syncthreads();
  int cg = tid % CG, rg = tid / CG;
  int j0 = cg * 4, r0 = rg * 4;
  float acc[4][4] = {};
  for (int k = 0; k < 128; k += 4) {
    alignas(16) float av[4][4];
#pragma unroll
    for (int m = 0; m < 4; m++)
      *(float4*)av[m] = *(const float4*)&xs[(r0 + m) * 128 + k];
#pragma unroll
    for (int i = 0; i < 4; i++) {
      float4 b = *(const float4*)&ws[(k + i) * MP + j0];
#pragma unroll
      for (int m = 0; m < 4; m++) {
        float a = av[m][i];
        acc[m][0] += a * b.x;
        acc[m][1] += a * b.y;
        acc[m][2] += a * b.z;
        acc[m][3] += a * b.w;
      }
    }
  }
  if (j0 < M) {
#pragma unroll
    for (int m = 0; m < 4; m++) {
      int gr = rowBase + r0 + m;
      if (gr < n) {
        float s = dinv[gr];
        float4 o = make_float4(acc[m][0] * s, acc[m][1] * s, acc[m][2] * s, acc[m][3] * s);
        *(float4*)&G[(size_t)gr * M + j0] = o;
      }
    }
  }
}

// ---------------- aggregation, 128 channels, fused bias+ReLU ----------------
// out[i] = relu(dinv[i]*(g[i] + sum_{e in row i} g[csr[e]]) + bias)
__global__ __launch_bounds__(256) void k_agg_relu128(const float* __restrict__ g, const int* __restrict__ csr,
                                                     const int* __restrict__ rp, const float* __restrict__ dinv,
                                                     const float* __restrict__ bias, float* __restrict__ out, int n) {
  int t = threadIdx.x;
  int node = blockIdx.x * 8 + (t >> 5);
  if (node >= n) return;
  int c4 = (t & 31) * 4;
  int e0 = rp[node], e1 = rp[node + 1];
  const float* gp = g + c4;
  float4 acc = *(const float4*)&gp[(size_t)node * 128];
  for (int e = e0; e < e1; ++e) {
    int s = csr[e];
    float4 v = *(const float4*)&gp[(size_t)s * 128];
    acc.x += v.x;
    acc.y += v.y;
    acc.z += v.z;
    acc.w += v.w;
  }
  float di = dinv[node];
  float4 bb = *(const float4*)&bias[c4];
  float4 o = make_float4(fmaxf(fmaf(di, acc.x, bb.x), 0.f),
                         fmaxf(fmaf(di, acc.y, bb.y), 0.f),
                         fmaxf(fmaf(di, acc.z, bb.z), 0.f),
                         fmaxf(fmaf(di, acc.w, bb.w), 0.f));
  *(float4*)&out[(size_t)node * 128 + c4] = o;
}

// ---------------- final aggregation (40 ch) + bias + log_softmax ----------------
__global__ __launch_bounds__(256) void k_agg_lsm40(const float* __restrict__ g, const int* __restrict__ csr,
                                                   const int* __restrict__ rp, const float* __restrict__ dinv,
                                                   const float* __restrict__ bias, float* __restrict__ out, int n) {
  int lane = threadIdx.x & 63;
  int node = blockIdx.x * 4 + (threadIdx.x >> 6);
  if (node >= n) return;
  int e0 = rp[node], e1 = rp[node + 1];
  bool act = lane < 40;
  float acc = 0.f;
  if (act) acc = g[(size_t)node * 40 + lane];
  for (int e = e0; e < e1; ++e) {
    int s = csr[e];
    if (act) acc += g[(size_t)s * 40 + lane];
  }
  float v = act ? fmaf(dinv[node], acc, bias[lane]) : -INFINITY;
  float m = v;
#pragma unroll
  for (int off = 32; off > 0; off >>= 1) m = fmaxf(m, __shfl_xor(m, off, 64));
  float ex = act ? __expf(v - m) : 0.f;
  float ssum = ex;
#pragma unroll
  for (int off = 32; off > 0; off >>= 1) ssum += __shfl_xor(ssum, off, 64);
  if (act) out[(size_t)node * 40 + lane] = v - m - __logf(ssum);
}

// ---------------- launch ----------------

extern "C" void kernel_launch(void* const* d_in, const int* in_sizes, int n_in,
                              void* d_out, int out_size, void* d_ws, size_t ws_size,
                              hipStream_t stream) {
  const float* x  = (const float*)d_in[0];
  const int*   ei = (const int*)d_in[1];
  const float* W1 = (const float*)d_in[2];
  const float* b1 = (const float*)d_in[3];
  const float* W2 = (const float*)d_in[4];
  const float* b2 = (const float*)d_in[5];
  const float* W3 = (const float*)d_in[6];
  const float* b3 = (const float*)d_in[7];
  float* out = (float*)d_out;
  int n = in_sizes[0] / 128;
  int E = in_sizes[1] / 2;
  const int* esrc = ei;
  const int* edst = ei + E;

  size_t off = 0;
  auto alloc = [&](size_t bytes) -> void* {
    void* r = (char*)d_ws + off;
    off += (bytes + 255) & ~(size_t)255;
    return r;
  };
  int*   cnt    = (int*)alloc((size_t)n * 4);
  int*   cursor = (int*)alloc((size_t)n * 4);
  int*   rp     = (int*)alloc((size_t)(n + 1) * 4);
  int*   bsum   = (int*)alloc(1024);
  float* dinv   = (float*)alloc((size_t)n * 4);
  int*   csr    = (int*)alloc((size_t)E * 4);
  float* bufA   = (float*)alloc((size_t)n * 128 * 4);
  float* bufB   = (float*)alloc((size_t)n * 128 * 4);

  hipMemsetAsync(cnt, 0, (size_t)n * 4, stream);
  hipMemsetAsync(cursor, 0, (size_t)n * 4, stream);

  int ge = (E + 255) / 256;
  int gn = (n + 255) / 256;  // 196 <= 256, single-block scan of block sums is valid
  k_count<<<ge, 256, 0, stream>>>(edst, cnt, E);
  k_dinv<<<gn, 256, 0, stream>>>(cnt, dinv, n);
  k_chunk_sum<<<gn, 256, 0, stream>>>(cnt, bsum, n);
  k_scan_bsum<<<1, 256, 0, stream>>>(bsum, gn);
  k_scan_final<<<gn, 256, 0, stream>>>(cnt, bsum, rp, n);
  k_scatter<<<ge, 256, 0, stream>>>(esrc, edst, rp, cursor, csr, E);

  // layer 1: g = dinv * (x @ W1); a = relu(dinv*agg(g) + b1)
  k_gemm_dinv<128, 128, 32><<<(n + 31) / 32, 256, 0, stream>>>(x, W1, dinv, bufA, n);
  k_agg_relu128<<<(n + 7) / 8, 256, 0, stream>>>(bufA, csr, rp, dinv, b1, bufB, n);
  // layer 2
  k_gemm_dinv<128, 128, 32><<<(n + 31) / 32, 256, 0, stream>>>(bufB, W2, dinv, bufA, n);
  k_agg_relu128<<<(n + 7) / 8, 256, 0, stream>>>(bufA, csr, rp, dinv, b2, bufB, n);
  // layer 3 + log_softmax
  k_gemm_dinv<40, 64, 64><<<(n + 63) / 64, 256, 0, stream>>>(bufB, W3, dinv, bufA, n);
  k_agg_lsm40<<<(n + 3) / 4, 256, 0, stream>>>(bufA, csr, rp, dinv, b3, out, n);
}

// Round 2
// 365.324 us; speedup vs baseline: 1.1558x; 1.1558x over previous
//
#include <hip/hip_runtime.h>
#include <cmath>

// ---------------- CSR build ----------------

__global__ __launch_bounds__(256) void k_count(const int* __restrict__ dst, int* __restrict__ cnt, int E) {
  int e = blockIdx.x * 256 + threadIdx.x;
  if (e < E) atomicAdd(&cnt[dst[e]], 1);
}

__global__ __launch_bounds__(256) void k_dinv(const int* __restrict__ cnt, float* __restrict__ dinv, int n) {
  int i = blockIdx.x * 256 + threadIdx.x;
  if (i < n) dinv[i] = rsqrtf((float)(cnt[i] + 1));  // +1 = self loop
}

__global__ __launch_bounds__(256) void k_chunk_sum(const int* __restrict__ cnt, int* __restrict__ bsum, int n) {
  __shared__ int s[256];
  int i = blockIdx.x * 256 + threadIdx.x;
  s[threadIdx.x] = (i < n) ? cnt[i] : 0;
  __syncthreads();
  for (int off = 128; off > 0; off >>= 1) {
    if (threadIdx.x < off) s[threadIdx.x] += s[threadIdx.x + off];
    __syncthreads();
  }
  if (threadIdx.x == 0) bsum[blockIdx.x] = s[0];
}

__global__ __launch_bounds__(256) void k_scan_bsum(int* __restrict__ bsum, int nb) {
  __shared__ int s[256];
  int t = threadIdx.x;
  int v = (t < nb) ? bsum[t] : 0;
  s[t] = v;
  __syncthreads();
  for (int off = 1; off < 256; off <<= 1) {
    int u = (t >= off) ? s[t - off] : 0;
    __syncthreads();
    s[t] += u;
    __syncthreads();
  }
  if (t < nb) bsum[t] = s[t] - v;  // exclusive
}

__global__ __launch_bounds__(256) void k_scan_final(const int* __restrict__ cnt, const int* __restrict__ boff,
                                                    int* __restrict__ rp, int n) {
  __shared__ int s[256];
  int t = threadIdx.x;
  int i = blockIdx.x * 256 + t;
  int v = (i < n) ? cnt[i] : 0;
  s[t] = v;
  __syncthreads();
  for (int off = 1; off < 256; off <<= 1) {
    int u = (t >= off) ? s[t - off] : 0;
    __syncthreads();
    s[t] += u;
    __syncthreads();
  }
  int excl = s[t] - v + boff[blockIdx.x];
  if (i < n) rp[i] = excl;
  if (i == n - 1) rp[n] = excl + v;
}

__global__ __launch_bounds__(256) void k_scatter(const int* __restrict__ src, const int* __restrict__ dst,
                                                 const int* __restrict__ rp, int* __restrict__ cursor,
                                                 int* __restrict__ csr, int E) {
  int e = blockIdx.x * 256 + threadIdx.x;
  if (e < E) {
    int d = dst[e];
    int p = rp[d] + atomicAdd(&cursor[d], 1);
    csr[p] = src[e];
  }
}

// ---------------- GEMM with fused dinv row-scale ----------------
// G[i][:] = dinv[i] * (X[i][:] @ W)   X:[n][128], W:[128][M] row-major, G:[n][M]
template <int M, int MP, int ROWS>
__global__ __launch_bounds__(256) void k_gemm_dinv(const float* __restrict__ X, const float* __restrict__ W,
                                                   const float* __restrict__ dinv, float* __restrict__ G, int n) {
  constexpr int CG = MP / 4;    // col groups of 4
  constexpr int RG = 256 / CG;  // row groups of 4
  static_assert(ROWS == RG * 4, "geometry");
  __shared__ float ws[128 * MP];
  __shared__ float xs[ROWS * 128];
  int tid = threadIdx.x;
  if constexpr (M == MP) {
    for (int idx = tid * 4; idx < 128 * M; idx += 1024)
      *(float4*)&ws[idx] = *(const float4*)&W[idx];
  } else {
    for (int idx = tid; idx < 128 * MP; idx += 256) {
      int k = idx / MP, j = idx - k * MP;
      ws[idx] = (j < M) ? W[k * M + j] : 0.f;
    }
  }
  int rowBase = blockIdx.x * ROWS;
  for (int idx = tid * 4; idx < ROWS * 128; idx += 1024) {
    int r = idx >> 7;
    int gr = rowBase + r;
    float4 v = make_float4(0.f, 0.f, 0.f, 0.f);
    if (gr < n) v = *(const float4*)&X[(size_t)gr * 128 + (idx & 127)];
    *(float4*)&xs[idx] = v;
  }
  __syncthreads();
  int cg = tid % CG, rg = tid / CG;
  int j0 = cg * 4, r0 = rg * 4;
  float acc[4][4] = {};
  for (int k = 0; k < 128; k += 4) {
    alignas(16) float av[4][4];
#pragma unroll
    for (int m = 0; m < 4; m++)
      *(float4*)av[m] = *(const float4*)&xs[(r0 + m) * 128 + k];
#pragma unroll
    for (int i = 0; i < 4; i++) {
      float4 b = *(const float4*)&ws[(k + i) * MP + j0];
#pragma unroll
      for (int m = 0; m < 4; m++) {
        float a = av[m][i];
        acc[m][0] += a * b.x;
        acc[m][1] += a * b.y;
        acc[m][2] += a * b.z;
        acc[m][3] += a * b.w;
      }
    }
  }
  if (j0 < M) {
#pragma unroll
    for (int m = 0; m < 4; m++) {
      int gr = rowBase + r0 + m;
      if (gr < n) {
        float s = dinv[gr];
        float4 o = make_float4(acc[m][0] * s, acc[m][1] * s, acc[m][2] * s, acc[m][3] * s);
        *(float4*)&G[(size_t)gr * M + j0] = o;
      }
    }
  }
}

// ---------------- aggregation, 128 channels, fused bias+ReLU ----------------
// out[i] = relu(dinv[i]*(g[i] + sum_{e in row i} g[csr[e]]) + bias)
// Edge loop unrolled x8 with independent accumulators -> 8 gathers in flight.
__global__ __launch_bounds__(256) void k_agg_relu128(const float* __restrict__ g, const int* __restrict__ csr,
                                                     const int* __restrict__ rp, const float* __restrict__ dinv,
                                                     const float* __restrict__ bias, float* __restrict__ out, int n) {
  int t = threadIdx.x;
  int node = blockIdx.x * 8 + (t >> 5);
  if (node >= n) return;
  int c4 = (t & 31) * 4;
  int e0 = rp[node], e1 = rp[node + 1];
  const float* gp = g + c4;

  float4 a[8];
  a[0] = *(const float4*)&gp[(size_t)node * 128];  // self loop
#pragma unroll
  for (int u = 1; u < 8; u++) a[u] = make_float4(0.f, 0.f, 0.f, 0.f);

  int e = e0;
  for (; e + 8 <= e1; e += 8) {
    int s[8];
#pragma unroll
    for (int u = 0; u < 8; u++) s[u] = csr[e + u];
#pragma unroll
    for (int u = 0; u < 8; u++) {
      float4 v = *(const float4*)&gp[(size_t)s[u] * 128];
      a[u].x += v.x; a[u].y += v.y; a[u].z += v.z; a[u].w += v.w;
    }
  }
  for (; e < e1; ++e) {
    int s = csr[e];
    float4 v = *(const float4*)&gp[(size_t)s * 128];
    a[0].x += v.x; a[0].y += v.y; a[0].z += v.z; a[0].w += v.w;
  }
#pragma unroll
  for (int u = 4; u < 8; u++) {
    a[u - 4].x += a[u].x; a[u - 4].y += a[u].y; a[u - 4].z += a[u].z; a[u - 4].w += a[u].w;
  }
#pragma unroll
  for (int u = 2; u < 4; u++) {
    a[u - 2].x += a[u].x; a[u - 2].y += a[u].y; a[u - 2].z += a[u].z; a[u - 2].w += a[u].w;
  }
  float4 acc = make_float4(a[0].x + a[1].x, a[0].y + a[1].y, a[0].z + a[1].z, a[0].w + a[1].w);

  float di = dinv[node];
  float4 bb = *(const float4*)&bias[c4];
  float4 o = make_float4(fmaxf(fmaf(di, acc.x, bb.x), 0.f),
                         fmaxf(fmaf(di, acc.y, bb.y), 0.f),
                         fmaxf(fmaf(di, acc.z, bb.z), 0.f),
                         fmaxf(fmaf(di, acc.w, bb.w), 0.f));
  *(float4*)&out[(size_t)node * 128 + c4] = o;
}

// ---------------- final aggregation (40 ch) + bias + log_softmax ----------------
// NOTE: loads are unpredicated for lanes 40..63 (reads spill into the next
// row / allocated slack of the n*128-float buffer) and masked at the end.
__global__ __launch_bounds__(256) void k_agg_lsm40(const float* __restrict__ g, const int* __restrict__ csr,
                                                   const int* __restrict__ rp, const float* __restrict__ dinv,
                                                   const float* __restrict__ bias, float* __restrict__ out, int n) {
  int lane = threadIdx.x & 63;
  int node = blockIdx.x * 4 + (threadIdx.x >> 6);
  if (node >= n) return;
  int e0 = rp[node], e1 = rp[node + 1];

  float a[8];
  a[0] = g[(size_t)node * 40 + lane];  // self loop (garbage in lanes >=40, masked later)
#pragma unroll
  for (int u = 1; u < 8; u++) a[u] = 0.f;

  int e = e0;
  for (; e + 8 <= e1; e += 8) {
    int s[8];
#pragma unroll
    for (int u = 0; u < 8; u++) s[u] = csr[e + u];
#pragma unroll
    for (int u = 0; u < 8; u++) a[u] += g[(size_t)s[u] * 40 + lane];
  }
  for (; e < e1; ++e) a[0] += g[(size_t)csr[e] * 40 + lane];

  float acc = ((a[0] + a[1]) + (a[2] + a[3])) + ((a[4] + a[5]) + (a[6] + a[7]));

  bool act = lane < 40;
  float v = act ? fmaf(dinv[node], acc, bias[lane]) : -INFINITY;
  float m = v;
#pragma unroll
  for (int off = 32; off > 0; off >>= 1) m = fmaxf(m, __shfl_xor(m, off, 64));
  float ex = act ? __expf(v - m) : 0.f;
  float ssum = ex;
#pragma unroll
  for (int off = 32; off > 0; off >>= 1) ssum += __shfl_xor(ssum, off, 64);
  if (act) out[(size_t)node * 40 + lane] = v - m - __logf(ssum);
}

// ---------------- launch ----------------

extern "C" void kernel_launch(void* const* d_in, const int* in_sizes, int n_in,
                              void* d_out, int out_size, void* d_ws, size_t ws_size,
                              hipStream_t stream) {
  const float* x  = (const float*)d_in[0];
  const int*   ei = (const int*)d_in[1];
  const float* W1 = (const float*)d_in[2];
  const float* b1 = (const float*)d_in[3];
  const float* W2 = (const float*)d_in[4];
  const float* b2 = (const float*)d_in[5];
  const float* W3 = (const float*)d_in[6];
  const float* b3 = (const float*)d_in[7];
  float* out = (float*)d_out;
  int n = in_sizes[0] / 128;
  int E = in_sizes[1] / 2;
  const int* esrc = ei;
  const int* edst = ei + E;

  size_t off = 0;
  auto alloc = [&](size_t bytes) -> void* {
    void* r = (char*)d_ws + off;
    off += (bytes + 255) & ~(size_t)255;
    return r;
  };
  int*   cnt    = (int*)alloc((size_t)n * 4);
  int*   cursor = (int*)alloc((size_t)n * 4);
  int*   rp     = (int*)alloc((size_t)(n + 1) * 4);
  int*   bsum   = (int*)alloc(1024);
  float* dinv   = (float*)alloc((size_t)n * 4);
  int*   csr    = (int*)alloc((size_t)E * 4);
  float* bufA   = (float*)alloc((size_t)n * 128 * 4);
  float* bufB   = (float*)alloc((size_t)n * 128 * 4);

  hipMemsetAsync(cnt, 0, (size_t)n * 4, stream);
  hipMemsetAsync(cursor, 0, (size_t)n * 4, stream);

  int ge = (E + 255) / 256;
  int gn = (n + 255) / 256;  // 196 <= 256, single-block scan of block sums is valid
  k_count<<<ge, 256, 0, stream>>>(edst, cnt, E);
  k_dinv<<<gn, 256, 0, stream>>>(cnt, dinv, n);
  k_chunk_sum<<<gn, 256, 0, stream>>>(cnt, bsum, n);
  k_scan_bsum<<<1, 256, 0, stream>>>(bsum, gn);
  k_scan_final<<<gn, 256, 0, stream>>>(cnt, bsum, rp, n);
  k_scatter<<<ge, 256, 0, stream>>>(esrc, edst, rp, cursor, csr, E);

  // layer 1: g = dinv * (x @ W1); a = relu(dinv*agg(g) + b1)
  k_gemm_dinv<128, 128, 32><<<(n + 31) / 32, 256, 0, stream>>>(x, W1, dinv, bufA, n);
  k_agg_relu128<<<(n + 7) / 8, 256, 0, stream>>>(bufA, csr, rp, dinv, b1, bufB, n);
  // layer 2
  k_gemm_dinv<128, 128, 32><<<(n + 31) / 32, 256, 0, stream>>>(bufB, W2, dinv, bufA, n);
  k_agg_relu128<<<(n + 7) / 8, 256, 0, stream>>>(bufA, csr, rp, dinv, b2, bufB, n);
  // layer 3 + log_softmax
  k_gemm_dinv<40, 64, 64><<<(n + 63) / 64, 256, 0, stream>>>(bufB, W3, dinv, bufA, n);
  k_agg_lsm40<<<(n + 3) / 4, 256, 0, stream>>>(bufA, csr, rp, dinv, b3, out, n);
}

// Round 3
// 316.107 us; speedup vs baseline: 1.3358x; 1.1557x over previous
//
#include <hip/hip_runtime.h>
#include <cmath>

// ---- bf16 helpers (RNE) ----
__device__ __forceinline__ unsigned short f2bf(float f) {
  unsigned u = __float_as_uint(f);
  u = (u + 0x7FFFu + ((u >> 16) & 1u)) >> 16;
  return (unsigned short)u;
}
__device__ __forceinline__ unsigned pack2(float a, float b) {
  return (unsigned)f2bf(a) | ((unsigned)f2bf(b) << 16);
}
__device__ __forceinline__ float bflo(unsigned u) { return __uint_as_float(u << 16); }
__device__ __forceinline__ float bfhi(unsigned u) { return __uint_as_float(u & 0xFFFF0000u); }
__device__ __forceinline__ float bf1(unsigned short h) { return __uint_as_float((unsigned)h << 16); }

// ---------------- CSR build ----------------

__global__ __launch_bounds__(256) void k_count(const int* __restrict__ dst, int* __restrict__ cnt, int E) {
  int e = blockIdx.x * 256 + threadIdx.x;
  if (e < E) atomicAdd(&cnt[dst[e]], 1);
}

__global__ __launch_bounds__(256) void k_chunk_sum(const int* __restrict__ cnt, int* __restrict__ bsum, int n) {
  __shared__ int s[256];
  int i = blockIdx.x * 256 + threadIdx.x;
  s[threadIdx.x] = (i < n) ? cnt[i] : 0;
  __syncthreads();
  for (int off = 128; off > 0; off >>= 1) {
    if (threadIdx.x < off) s[threadIdx.x] += s[threadIdx.x + off];
    __syncthreads();
  }
  if (threadIdx.x == 0) bsum[blockIdx.x] = s[0];
}

__global__ __launch_bounds__(256) void k_scan_bsum(int* __restrict__ bsum, int nb) {
  __shared__ int s[256];
  int t = threadIdx.x;
  int v = (t < nb) ? bsum[t] : 0;
  s[t] = v;
  __syncthreads();
  for (int off = 1; off < 256; off <<= 1) {
    int u = (t >= off) ? s[t - off] : 0;
    __syncthreads();
    s[t] += u;
    __syncthreads();
  }
  if (t < nb) bsum[t] = s[t] - v;  // exclusive
}

// also emits dinv = rsqrt(cnt+1)
__global__ __launch_bounds__(256) void k_scan_final(const int* __restrict__ cnt, const int* __restrict__ boff,
                                                    int* __restrict__ rp, float* __restrict__ dinv, int n) {
  __shared__ int s[256];
  int t = threadIdx.x;
  int i = blockIdx.x * 256 + t;
  int v = (i < n) ? cnt[i] : 0;
  s[t] = v;
  __syncthreads();
  for (int off = 1; off < 256; off <<= 1) {
    int u = (t >= off) ? s[t - off] : 0;
    __syncthreads();
    s[t] += u;
    __syncthreads();
  }
  int excl = s[t] - v + boff[blockIdx.x];
  if (i < n) {
    rp[i] = excl;
    dinv[i] = rsqrtf((float)(v + 1));
  }
  if (i == n - 1) rp[n] = excl + v;
}

__global__ __launch_bounds__(256) void k_scatter(const int* __restrict__ src, const int* __restrict__ dst,
                                                 const int* __restrict__ rp, int* __restrict__ cursor,
                                                 int* __restrict__ csr, int E) {
  int e = blockIdx.x * 256 + threadIdx.x;
  if (e < E) {
    int d = dst[e];
    int p = rp[d] + atomicAdd(&cursor[d], 1);
    csr[p] = src[e];
  }
}

// ---------------- GEMM with fused dinv row-scale, bf16 output ----------------
// G[i][:] = bf16( dinv[i] * (X[i][:] @ W) )   X:[n][128] (f32 or bf16), W:[128][M] f32 row-major
template <int M, int MP, int ROWS, bool BF16IN>
__global__ __launch_bounds__(256) void k_gemm_dinv(const void* __restrict__ Xv, const float* __restrict__ W,
                                                   const float* __restrict__ dinv, unsigned short* __restrict__ G,
                                                   int n) {
  constexpr int CG = MP / 4;    // col groups of 4
  constexpr int RG = 256 / CG;  // row groups of 4
  static_assert(ROWS == RG * 4, "geometry");
  __shared__ float ws[128 * MP];
  __shared__ float xs[ROWS * 128];
  int tid = threadIdx.x;
  if constexpr (M == MP) {
    for (int idx = tid * 4; idx < 128 * M; idx += 1024)
      *(float4*)&ws[idx] = *(const float4*)&W[idx];
  } else {
    for (int idx = tid; idx < 128 * MP; idx += 256) {
      int k = idx / MP, j = idx - k * MP;
      ws[idx] = (j < M) ? W[k * M + j] : 0.f;
    }
  }
  int rowBase = blockIdx.x * ROWS;
  if constexpr (BF16IN) {
    const unsigned short* X = (const unsigned short*)Xv;
    for (int idx = tid * 8; idx < ROWS * 128; idx += 2048) {
      int r = idx >> 7;
      int gr = rowBase + r;
      uint4 v = make_uint4(0u, 0u, 0u, 0u);
      if (gr < n) v = *(const uint4*)&X[(size_t)gr * 128 + (idx & 127)];
      float4 lo = make_float4(bflo(v.x), bfhi(v.x), bflo(v.y), bfhi(v.y));
      float4 hi = make_float4(bflo(v.z), bfhi(v.z), bflo(v.w), bfhi(v.w));
      *(float4*)&xs[idx] = lo;
      *(float4*)&xs[idx + 4] = hi;
    }
  } else {
    const float* X = (const float*)Xv;
    for (int idx = tid * 4; idx < ROWS * 128; idx += 1024) {
      int r = idx >> 7;
      int gr = rowBase + r;
      float4 v = make_float4(0.f, 0.f, 0.f, 0.f);
      if (gr < n) v = *(const float4*)&X[(size_t)gr * 128 + (idx & 127)];
      *(float4*)&xs[idx] = v;
    }
  }
  __syncthreads();
  int cg = tid % CG, rg = tid / CG;
  int j0 = cg * 4, r0 = rg * 4;
  float acc[4][4] = {};
  for (int k = 0; k < 128; k += 4) {
    alignas(16) float av[4][4];
#pragma unroll
    for (int m = 0; m < 4; m++)
      *(float4*)av[m] = *(const float4*)&xs[(r0 + m) * 128 + k];
#pragma unroll
    for (int i = 0; i < 4; i++) {
      float4 b = *(const float4*)&ws[(k + i) * MP + j0];
#pragma unroll
      for (int m = 0; m < 4; m++) {
        float a = av[m][i];
        acc[m][0] += a * b.x;
        acc[m][1] += a * b.y;
        acc[m][2] += a * b.z;
        acc[m][3] += a * b.w;
      }
    }
  }
  if (j0 < M) {
#pragma unroll
    for (int m = 0; m < 4; m++) {
      int gr = rowBase + r0 + m;
      if (gr < n) {
        float s = dinv[gr];
        uint2 o;
        o.x = pack2(acc[m][0] * s, acc[m][1] * s);
        o.y = pack2(acc[m][2] * s, acc[m][3] * s);
        *(uint2*)&G[(size_t)gr * M + j0] = o;
      }
    }
  }
}

// ---------------- aggregation, 128 ch bf16, fused bias+ReLU, bf16 out ----------------
// out[i] = bf16(relu(dinv[i]*(g[i] + sum_{e} g[csr[e]]) + bias))
__global__ __launch_bounds__(256) void k_agg_relu128(const unsigned short* __restrict__ g,
                                                     const int* __restrict__ csr, const int* __restrict__ rp,
                                                     const float* __restrict__ dinv, const float* __restrict__ bias,
                                                     unsigned short* __restrict__ out, int n) {
  int t = threadIdx.x;
  int node = blockIdx.x * 8 + (t >> 5);
  if (node >= n) return;
  int c4 = (t & 31) * 4;
  int e0 = rp[node], e1 = rp[node + 1];
  const unsigned short* gp = g + c4;

  float4 a[8];
  {
    uint2 v = *(const uint2*)&gp[(size_t)node * 128];  // self loop
    a[0] = make_float4(bflo(v.x), bfhi(v.x), bflo(v.y), bfhi(v.y));
  }
#pragma unroll
  for (int u = 1; u < 8; u++) a[u] = make_float4(0.f, 0.f, 0.f, 0.f);

  int e = e0;
  for (; e + 8 <= e1; e += 8) {
    int s[8];
#pragma unroll
    for (int u = 0; u < 8; u++) s[u] = csr[e + u];
#pragma unroll
    for (int u = 0; u < 8; u++) {
      uint2 v = *(const uint2*)&gp[(size_t)s[u] * 128];
      a[u].x += bflo(v.x); a[u].y += bfhi(v.x); a[u].z += bflo(v.y); a[u].w += bfhi(v.y);
    }
  }
  for (; e < e1; ++e) {
    int s = csr[e];
    uint2 v = *(const uint2*)&gp[(size_t)s * 128];
    a[0].x += bflo(v.x); a[0].y += bfhi(v.x); a[0].z += bflo(v.y); a[0].w += bfhi(v.y);
  }
#pragma unroll
  for (int u = 4; u < 8; u++) {
    a[u - 4].x += a[u].x; a[u - 4].y += a[u].y; a[u - 4].z += a[u].z; a[u - 4].w += a[u].w;
  }
#pragma unroll
  for (int u = 2; u < 4; u++) {
    a[u - 2].x += a[u].x; a[u - 2].y += a[u].y; a[u - 2].z += a[u].z; a[u - 2].w += a[u].w;
  }
  float4 acc = make_float4(a[0].x + a[1].x, a[0].y + a[1].y, a[0].z + a[1].z, a[0].w + a[1].w);

  float di = dinv[node];
  float4 bb = *(const float4*)&bias[c4];
  uint2 o;
  o.x = pack2(fmaxf(fmaf(di, acc.x, bb.x), 0.f), fmaxf(fmaf(di, acc.y, bb.y), 0.f));
  o.y = pack2(fmaxf(fmaf(di, acc.z, bb.z), 0.f), fmaxf(fmaf(di, acc.w, bb.w), 0.f));
  *(uint2*)&out[(size_t)node * 128 + c4] = o;
}

// ---------------- final aggregation (40 ch bf16) + bias + log_softmax, f32 out ----------------
// Loads unpredicated for lanes 40..63 (buffer has slack), masked at the end.
__global__ __launch_bounds__(256) void k_agg_lsm40(const unsigned short* __restrict__ g,
                                                   const int* __restrict__ csr, const int* __restrict__ rp,
                                                   const float* __restrict__ dinv, const float* __restrict__ bias,
                                                   float* __restrict__ out, int n) {
  int lane = threadIdx.x & 63;
  int node = blockIdx.x * 4 + (threadIdx.x >> 6);
  if (node >= n) return;
  int e0 = rp[node], e1 = rp[node + 1];

  float a[8];
  a[0] = bf1(g[(size_t)node * 40 + lane]);  // self loop (garbage lanes >=40, masked later)
#pragma unroll
  for (int u = 1; u < 8; u++) a[u] = 0.f;

  int e = e0;
  for (; e + 8 <= e1; e += 8) {
    int s[8];
#pragma unroll
    for (int u = 0; u < 8; u++) s[u] = csr[e + u];
#pragma unroll
    for (int u = 0; u < 8; u++) a[u] += bf1(g[(size_t)s[u] * 40 + lane]);
  }
  for (; e < e1; ++e) a[0] += bf1(g[(size_t)csr[e] * 40 + lane]);

  float acc = ((a[0] + a[1]) + (a[2] + a[3])) + ((a[4] + a[5]) + (a[6] + a[7]));

  bool act = lane < 40;
  float v = act ? fmaf(dinv[node], acc, bias[lane]) : -INFINITY;
  float m = v;
#pragma unroll
  for (int off = 32; off > 0; off >>= 1) m = fmaxf(m, __shfl_xor(m, off, 64));
  float ex = act ? __expf(v - m) : 0.f;
  float ssum = ex;
#pragma unroll
  for (int off = 32; off > 0; off >>= 1) ssum += __shfl_xor(ssum, off, 64);
  if (act) out[(size_t)node * 40 + lane] = v - m - __logf(ssum);
}

// ---------------- launch ----------------

extern "C" void kernel_launch(void* const* d_in, const int* in_sizes, int n_in,
                              void* d_out, int out_size, void* d_ws, size_t ws_size,
                              hipStream_t stream) {
  const float* x  = (const float*)d_in[0];
  const int*   ei = (const int*)d_in[1];
  const float* W1 = (const float*)d_in[2];
  const float* b1 = (const float*)d_in[3];
  const float* W2 = (const float*)d_in[4];
  const float* b2 = (const float*)d_in[5];
  const float* W3 = (const float*)d_in[6];
  const float* b3 = (const float*)d_in[7];
  float* out = (float*)d_out;
  int n = in_sizes[0] / 128;
  int E = in_sizes[1] / 2;
  const int* esrc = ei;
  const int* edst = ei + E;

  size_t off = 0;
  auto alloc = [&](size_t bytes) -> void* {
    void* r = (char*)d_ws + off;
    off += (bytes + 255) & ~(size_t)255;
    return r;
  };
  int*   cnt    = (int*)alloc((size_t)n * 4);
  int*   cursor = (int*)alloc((size_t)n * 4);
  int*   rp     = (int*)alloc((size_t)(n + 1) * 4);
  int*   bsum   = (int*)alloc(1024);
  float* dinv   = (float*)alloc((size_t)n * 4);
  int*   csr    = (int*)alloc((size_t)E * 4);
  unsigned short* bufA = (unsigned short*)alloc((size_t)n * 128 * 4);  // slack for lsm40 over-read
  unsigned short* bufB = (unsigned short*)alloc((size_t)n * 128 * 4);

  hipMemsetAsync(cnt, 0, (size_t)n * 4, stream);
  hipMemsetAsync(cursor, 0, (size_t)n * 4, stream);

  int ge = (E + 255) / 256;
  int gn = (n + 255) / 256;  // 196 <= 256, single-block scan of block sums is valid
  k_count<<<ge, 256, 0, stream>>>(edst, cnt, E);
  k_chunk_sum<<<gn, 256, 0, stream>>>(cnt, bsum, n);
  k_scan_bsum<<<1, 256, 0, stream>>>(bsum, gn);
  k_scan_final<<<gn, 256, 0, stream>>>(cnt, bsum, rp, dinv, n);
  k_scatter<<<ge, 256, 0, stream>>>(esrc, edst, rp, cursor, csr, E);

  // layer 1: g = bf16(dinv * (x @ W1)); a = bf16(relu(dinv*agg(g) + b1))
  k_gemm_dinv<128, 128, 32, false><<<(n + 31) / 32, 256, 0, stream>>>(x, W1, dinv, bufA, n);
  k_agg_relu128<<<(n + 7) / 8, 256, 0, stream>>>(bufA, csr, rp, dinv, b1, bufB, n);
  // layer 2
  k_gemm_dinv<128, 128, 32, true><<<(n + 31) / 32, 256, 0, stream>>>(bufB, W2, dinv, bufA, n);
  k_agg_relu128<<<(n + 7) / 8, 256, 0, stream>>>(bufA, csr, rp, dinv, b2, bufB, n);
  // layer 3 + log_softmax
  k_gemm_dinv<40, 64, 64, true><<<(n + 63) / 64, 256, 0, stream>>>(bufB, W3, dinv, bufA, n);
  k_agg_lsm40<<<(n + 3) / 4, 256, 0, stream>>>(bufA, csr, rp, dinv, b3, out, n);
}

// Round 4
// 262.410 us; speedup vs baseline: 1.6091x; 1.2046x over previous
//
#include <hip/hip_runtime.h>
#include <cmath>

// ---- bf16 helpers (RNE) ----
__device__ __forceinline__ unsigned short f2bf(float f) {
  unsigned u = __float_as_uint(f);
  u = (u + 0x7FFFu + ((u >> 16) & 1u)) >> 16;
  return (unsigned short)u;
}
__device__ __forceinline__ unsigned pack2(float a, float b) {
  return (unsigned)f2bf(a) | ((unsigned)f2bf(b) << 16);
}
__device__ __forceinline__ float bflo(unsigned u) { return __uint_as_float(u << 16); }
__device__ __forceinline__ float bfhi(unsigned u) { return __uint_as_float(u & 0xFFFF0000u); }
__device__ __forceinline__ float bf1(unsigned short h) { return __uint_as_float((unsigned)h << 16); }

using bh8 = __attribute__((ext_vector_type(8))) short;    // 8 bf16 = 4 VGPR (MFMA A/B frag)
using f32x4 = __attribute__((ext_vector_type(4))) float;  // MFMA C/D frag

// ---------------- CSR build ----------------

__global__ __launch_bounds__(256) void k_count(const int* __restrict__ dst, int* __restrict__ cnt, int E) {
  int e = blockIdx.x * 256 + threadIdx.x;
  if (e < E) atomicAdd(&cnt[dst[e]], 1);
}

__global__ __launch_bounds__(256) void k_chunk_sum(const int* __restrict__ cnt, int* __restrict__ bsum, int n) {
  __shared__ int s[256];
  int i = blockIdx.x * 256 + threadIdx.x;
  s[threadIdx.x] = (i < n) ? cnt[i] : 0;
  __syncthreads();
  for (int off = 128; off > 0; off >>= 1) {
    if (threadIdx.x < off) s[threadIdx.x] += s[threadIdx.x + off];
    __syncthreads();
  }
  if (threadIdx.x == 0) bsum[blockIdx.x] = s[0];
}

__global__ __launch_bounds__(256) void k_scan_bsum(int* __restrict__ bsum, int nb) {
  __shared__ int s[256];
  int t = threadIdx.x;
  int v = (t < nb) ? bsum[t] : 0;
  s[t] = v;
  __syncthreads();
  for (int off = 1; off < 256; off <<= 1) {
    int u = (t >= off) ? s[t - off] : 0;
    __syncthreads();
    s[t] += u;
    __syncthreads();
  }
  if (t < nb) bsum[t] = s[t] - v;  // exclusive
}

// also emits dinv = rsqrt(cnt+1)
__global__ __launch_bounds__(256) void k_scan_final(const int* __restrict__ cnt, const int* __restrict__ boff,
                                                    int* __restrict__ rp, float* __restrict__ dinv, int n) {
  __shared__ int s[256];
  int t = threadIdx.x;
  int i = blockIdx.x * 256 + t;
  int v = (i < n) ? cnt[i] : 0;
  s[t] = v;
  __syncthreads();
  for (int off = 1; off < 256; off <<= 1) {
    int u = (t >= off) ? s[t - off] : 0;
    __syncthreads();
    s[t] += u;
    __syncthreads();
  }
  int excl = s[t] - v + boff[blockIdx.x];
  if (i < n) {
    rp[i] = excl;
    dinv[i] = rsqrtf((float)(v + 1));
  }
  if (i == n - 1) rp[n] = excl + v;
}

__global__ __launch_bounds__(256) void k_scatter(const int* __restrict__ src, const int* __restrict__ dst,
                                                 const int* __restrict__ rp, int* __restrict__ cursor,
                                                 int* __restrict__ csr, int E) {
  int e = blockIdx.x * 256 + threadIdx.x;
  if (e < E) {
    int d = dst[e];
    int p = rp[d] + atomicAdd(&cursor[d], 1);
    csr[p] = src[e];
  }
}

// ---------------- conversions ----------------

__global__ __launch_bounds__(256) void k_f2b(const float* __restrict__ x, unsigned short* __restrict__ xb, int total4) {
  int i = blockIdx.x * 256 + threadIdx.x;
  if (i < total4) {
    float4 v = *(const float4*)&x[(size_t)i * 4];
    uint2 o;
    o.x = pack2(v.x, v.y);
    o.y = pack2(v.z, v.w);
    *(uint2*)&xb[(size_t)i * 4] = o;
  }
}

// W[k][c] f32 (128 x M) -> Wt[c][k] bf16 (MP x 128), rows >= M zero-padded
__global__ __launch_bounds__(256) void k_wt(const float* __restrict__ W, unsigned short* __restrict__ Wt, int M, int MP) {
  int i = blockIdx.x * 256 + threadIdx.x;
  if (i < MP * 128) {
    int c = i >> 7, k = i & 127;
    Wt[i] = (c < M) ? f2bf(W[(size_t)k * M + c]) : (unsigned short)0;
  }
}

// ---------------- MFMA GEMM, fused dinv row-scale, bf16 in/out ----------------
// G[i][:] = bf16( dinv[i] * (A[i][:] @ W) ),  A:[n][128] bf16, Wt:[cols][128] bf16 (pre-transposed)
// Wave computes 32 rows x (WT_N*16) cols. Block = 4 waves (NW_ROW x NW_COL grid of waves).
// No LDS: A and B fragments are direct 16B global loads in MFMA lane layout.
template <int WT_N, int NW_COL, int MOUT>
__global__ __launch_bounds__(256) void k_mfma_gemm(const unsigned short* __restrict__ A,
                                                   const unsigned short* __restrict__ Bt,
                                                   const float* __restrict__ dinv,
                                                   unsigned short* __restrict__ G, int n) {
  constexpr int NW_ROW = 4 / NW_COL;
  int tid = threadIdx.x;
  int wid = tid >> 6, lane = tid & 63;
  int lr = lane & 15, lq = lane >> 4;
  int wrow = wid / NW_COL, wcol = wid % NW_COL;
  int rowBase = blockIdx.x * (NW_ROW * 32) + wrow * 32;
  int colBase = wcol * (WT_N * 16);

  // A frags: af[rt][ks] holds A[rowBase+rt*16+lr][ks*32 + lq*8 .. +7]
  bh8 af[2][4];
#pragma unroll
  for (int rt = 0; rt < 2; rt++) {
    int row = rowBase + rt * 16 + lr;
    const unsigned short* ap = A + (size_t)row * 128 + lq * 8;
    bool ok = row < n;
#pragma unroll
    for (int ks = 0; ks < 4; ks++) {
      bh8 z = {0, 0, 0, 0, 0, 0, 0, 0};
      af[rt][ks] = ok ? *(const bh8*)(ap + ks * 32) : z;
    }
  }
  // B frags: bfr[ct][ks] holds Wt[colBase+ct*16+lr][ks*32 + lq*8 .. +7]
  bh8 bfr[WT_N][4];
#pragma unroll
  for (int ct = 0; ct < WT_N; ct++) {
    const unsigned short* bp = Bt + (size_t)(colBase + ct * 16 + lr) * 128 + lq * 8;
#pragma unroll
    for (int ks = 0; ks < 4; ks++) bfr[ct][ks] = *(const bh8*)(bp + ks * 32);
  }

  f32x4 acc[2][WT_N];
#pragma unroll
  for (int rt = 0; rt < 2; rt++)
#pragma unroll
    for (int ct = 0; ct < WT_N; ct++) acc[rt][ct] = (f32x4){0.f, 0.f, 0.f, 0.f};

#pragma unroll
  for (int ks = 0; ks < 4; ks++)
#pragma unroll
    for (int rt = 0; rt < 2; rt++)
#pragma unroll
      for (int ct = 0; ct < WT_N; ct++)
        acc[rt][ct] = __builtin_amdgcn_mfma_f32_16x16x32_bf16(af[rt][ks], bfr[ct][ks], acc[rt][ct], 0, 0, 0);

  // epilogue: C/D layout col=lane&15, row=(lane>>4)*4+reg  [guide-verified]
#pragma unroll
  for (int rt = 0; rt < 2; rt++)
#pragma unroll
    for (int r = 0; r < 4; r++) {
      int row = rowBase + rt * 16 + lq * 4 + r;
      if (row < n) {
        float di = dinv[row];
#pragma unroll
        for (int ct = 0; ct < WT_N; ct++) {
          int col = colBase + ct * 16 + lr;
          if (MOUT == 128 || col < MOUT)
            G[(size_t)row * MOUT + col] = f2bf(acc[rt][ct][r] * di);
        }
      }
    }
}

// ---------------- aggregation, 128 ch bf16, fused bias+ReLU, bf16 out ----------------
__global__ __launch_bounds__(256) void k_agg_relu128(const unsigned short* __restrict__ g,
                                                     const int* __restrict__ csr, const int* __restrict__ rp,
                                                     const float* __restrict__ dinv, const float* __restrict__ bias,
                                                     unsigned short* __restrict__ out, int n) {
  int t = threadIdx.x;
  int node = blockIdx.x * 8 + (t >> 5);
  if (node >= n) return;
  int c4 = (t & 31) * 4;
  int e0 = rp[node], e1 = rp[node + 1];
  const unsigned short* gp = g + c4;

  float4 a[8];
  {
    uint2 v = *(const uint2*)&gp[(size_t)node * 128];  // self loop
    a[0] = make_float4(bflo(v.x), bfhi(v.x), bflo(v.y), bfhi(v.y));
  }
#pragma unroll
  for (int u = 1; u < 8; u++) a[u] = make_float4(0.f, 0.f, 0.f, 0.f);

  int e = e0;
  for (; e + 8 <= e1; e += 8) {
    int s[8];
#pragma unroll
    for (int u = 0; u < 8; u++) s[u] = csr[e + u];
#pragma unroll
    for (int u = 0; u < 8; u++) {
      uint2 v = *(const uint2*)&gp[(size_t)s[u] * 128];
      a[u].x += bflo(v.x); a[u].y += bfhi(v.x); a[u].z += bflo(v.y); a[u].w += bfhi(v.y);
    }
  }
  for (; e < e1; ++e) {
    int s = csr[e];
    uint2 v = *(const uint2*)&gp[(size_t)s * 128];
    a[0].x += bflo(v.x); a[0].y += bfhi(v.x); a[0].z += bflo(v.y); a[0].w += bfhi(v.y);
  }
#pragma unroll
  for (int u = 4; u < 8; u++) {
    a[u - 4].x += a[u].x; a[u - 4].y += a[u].y; a[u - 4].z += a[u].z; a[u - 4].w += a[u].w;
  }
#pragma unroll
  for (int u = 2; u < 4; u++) {
    a[u - 2].x += a[u].x; a[u - 2].y += a[u].y; a[u - 2].z += a[u].z; a[u - 2].w += a[u].w;
  }
  float4 acc = make_float4(a[0].x + a[1].x, a[0].y + a[1].y, a[0].z + a[1].z, a[0].w + a[1].w);

  float di = dinv[node];
  float4 bb = *(const float4*)&bias[c4];
  uint2 o;
  o.x = pack2(fmaxf(fmaf(di, acc.x, bb.x), 0.f), fmaxf(fmaf(di, acc.y, bb.y), 0.f));
  o.y = pack2(fmaxf(fmaf(di, acc.z, bb.z), 0.f), fmaxf(fmaf(di, acc.w, bb.w), 0.f));
  *(uint2*)&out[(size_t)node * 128 + c4] = o;
}

// ---------------- final aggregation (40 ch bf16) + bias + log_softmax, f32 out ----------------
__global__ __launch_bounds__(256) void k_agg_lsm40(const unsigned short* __restrict__ g,
                                                   const int* __restrict__ csr, const int* __restrict__ rp,
                                                   const float* __restrict__ dinv, const float* __restrict__ bias,
                                                   float* __restrict__ out, int n) {
  int lane = threadIdx.x & 63;
  int node = blockIdx.x * 4 + (threadIdx.x >> 6);
  if (node >= n) return;
  int e0 = rp[node], e1 = rp[node + 1];

  float a[8];
  a[0] = bf1(g[(size_t)node * 40 + lane]);  // self loop (garbage lanes >=40, masked later)
#pragma unroll
  for (int u = 1; u < 8; u++) a[u] = 0.f;

  int e = e0;
  for (; e + 8 <= e1; e += 8) {
    int s[8];
#pragma unroll
    for (int u = 0; u < 8; u++) s[u] = csr[e + u];
#pragma unroll
    for (int u = 0; u < 8; u++) a[u] += bf1(g[(size_t)s[u] * 40 + lane]);
  }
  for (; e < e1; ++e) a[0] += bf1(g[(size_t)csr[e] * 40 + lane]);

  float acc = ((a[0] + a[1]) + (a[2] + a[3])) + ((a[4] + a[5]) + (a[6] + a[7]));

  bool act = lane < 40;
  float v = act ? fmaf(dinv[node], acc, bias[lane]) : -INFINITY;
  float m = v;
#pragma unroll
  for (int off = 32; off > 0; off >>= 1) m = fmaxf(m, __shfl_xor(m, off, 64));
  float ex = act ? __expf(v - m) : 0.f;
  float ssum = ex;
#pragma unroll
  for (int off = 32; off > 0; off >>= 1) ssum += __shfl_xor(ssum, off, 64);
  if (act) out[(size_t)node * 40 + lane] = v - m - __logf(ssum);
}

// ---------------- launch ----------------

extern "C" void kernel_launch(void* const* d_in, const int* in_sizes, int n_in,
                              void* d_out, int out_size, void* d_ws, size_t ws_size,
                              hipStream_t stream) {
  const float* x  = (const float*)d_in[0];
  const int*   ei = (const int*)d_in[1];
  const float* W1 = (const float*)d_in[2];
  const float* b1 = (const float*)d_in[3];
  const float* W2 = (const float*)d_in[4];
  const float* b2 = (const float*)d_in[5];
  const float* W3 = (const float*)d_in[6];
  const float* b3 = (const float*)d_in[7];
  float* out = (float*)d_out;
  int n = in_sizes[0] / 128;
  int E = in_sizes[1] / 2;
  const int* esrc = ei;
  const int* edst = ei + E;

  size_t off = 0;
  auto alloc = [&](size_t bytes) -> void* {
    void* r = (char*)d_ws + off;
    off += (bytes + 255) & ~(size_t)255;
    return r;
  };
  int*   cnt    = (int*)alloc((size_t)n * 4);
  int*   cursor = (int*)alloc((size_t)n * 4);
  int*   rp     = (int*)alloc((size_t)(n + 1) * 4);
  int*   bsum   = (int*)alloc(1024);
  float* dinv   = (float*)alloc((size_t)n * 4);
  int*   csr    = (int*)alloc((size_t)E * 4);
  unsigned short* xb   = (unsigned short*)alloc((size_t)n * 128 * 2 + 4096);  // +slack for OOB-row frag loads
  unsigned short* bufA = (unsigned short*)alloc((size_t)n * 128 * 2 + 4096);
  unsigned short* bufB = (unsigned short*)alloc((size_t)n * 128 * 2 + 4096);
  unsigned short* Wt1  = (unsigned short*)alloc(128 * 128 * 2);
  unsigned short* Wt2  = (unsigned short*)alloc(128 * 128 * 2);
  unsigned short* Wt3  = (unsigned short*)alloc(48 * 128 * 2);

  hipMemsetAsync(cnt, 0, (size_t)n * 4, stream);
  hipMemsetAsync(cursor, 0, (size_t)n * 4, stream);

  int ge = (E + 255) / 256;
  int gn = (n + 255) / 256;  // 196 <= 256, single-block scan of block sums is valid
  k_count<<<ge, 256, 0, stream>>>(edst, cnt, E);
  k_chunk_sum<<<gn, 256, 0, stream>>>(cnt, bsum, n);
  k_scan_bsum<<<1, 256, 0, stream>>>(bsum, gn);
  k_scan_final<<<gn, 256, 0, stream>>>(cnt, bsum, rp, dinv, n);
  k_scatter<<<ge, 256, 0, stream>>>(esrc, edst, rp, cursor, csr, E);

  // conversions
  int t4 = n * 128 / 4;
  k_f2b<<<(t4 + 255) / 256, 256, 0, stream>>>(x, xb, t4);
  k_wt<<<(128 * 128 + 255) / 256, 256, 0, stream>>>(W1, Wt1, 128, 128);
  k_wt<<<(128 * 128 + 255) / 256, 256, 0, stream>>>(W2, Wt2, 128, 128);
  k_wt<<<(48 * 128 + 255) / 256, 256, 0, stream>>>(W3, Wt3, 40, 48);

  // layer 1
  k_mfma_gemm<4, 2, 128><<<(n + 63) / 64, 256, 0, stream>>>(xb, Wt1, dinv, bufA, n);
  k_agg_relu128<<<(n + 7) / 8, 256, 0, stream>>>(bufA, csr, rp, dinv, b1, bufB, n);
  // layer 2
  k_mfma_gemm<4, 2, 128><<<(n + 63) / 64, 256, 0, stream>>>(bufB, Wt2, dinv, bufA, n);
  k_agg_relu128<<<(n + 7) / 8, 256, 0, stream>>>(bufA, csr, rp, dinv, b2, bufB, n);
  // layer 3 + log_softmax
  k_mfma_gemm<3, 1, 40><<<(n + 127) / 128, 256, 0, stream>>>(bufB, Wt3, dinv, bufA, n);
  k_agg_lsm40<<<(n + 3) / 4, 256, 0, stream>>>(bufA, csr, rp, dinv, b3, out, n);
}

// Round 5
// 256.713 us; speedup vs baseline: 1.6448x; 1.0222x over previous
//
#include <hip/hip_runtime.h>
#include <cmath>

// ---- bf16 helpers (RNE) ----
__device__ __forceinline__ unsigned short f2bf(float f) {
  unsigned u = __float_as_uint(f);
  u = (u + 0x7FFFu + ((u >> 16) & 1u)) >> 16;
  return (unsigned short)u;
}
__device__ __forceinline__ unsigned pack2(float a, float b) {
  return (unsigned)f2bf(a) | ((unsigned)f2bf(b) << 16);
}
__device__ __forceinline__ float bflo(unsigned u) { return __uint_as_float(u << 16); }
__device__ __forceinline__ float bfhi(unsigned u) { return __uint_as_float(u & 0xFFFF0000u); }
__device__ __forceinline__ float bf1(unsigned short h) { return __uint_as_float((unsigned)h << 16); }

using bh8 = __attribute__((ext_vector_type(8))) short;    // 8 bf16 = 4 VGPR (MFMA A/B frag)
using f32x4 = __attribute__((ext_vector_type(4))) float;  // MFMA C/D frag

// ---------------- CSR build (4-way split counters to cut atomic contention) ----------------

// count into cnt4[(e&3)*n + dst[e]] + fused x->bf16 conversion (streams under atomic stalls)
__global__ __launch_bounds__(256) void k_count_f2b(const int* __restrict__ dst, int* __restrict__ cnt4,
                                                   const float* __restrict__ x, unsigned short* __restrict__ xb,
                                                   int E, int n, int total4) {
  int tid = blockIdx.x * 256 + threadIdx.x;
  if (tid < E) atomicAdd(&cnt4[(size_t)(tid & 3) * n + dst[tid]], 1);
  int stride = gridDim.x * 256;
  for (int i = tid; i < total4; i += stride) {
    float4 v = *(const float4*)&x[(size_t)i * 4];
    uint2 o;
    o.x = pack2(v.x, v.y);
    o.y = pack2(v.z, v.w);
    *(uint2*)&xb[(size_t)i * 4] = o;
  }
}

__global__ __launch_bounds__(256) void k_chunk_sum(const int* __restrict__ cnt4, int* __restrict__ bsum, int n) {
  __shared__ int s[256];
  int i = blockIdx.x * 256 + threadIdx.x;
  int v = 0;
  if (i < n) v = cnt4[i] + cnt4[(size_t)n + i] + cnt4[2 * (size_t)n + i] + cnt4[3 * (size_t)n + i];
  s[threadIdx.x] = v;
  __syncthreads();
  for (int off = 128; off > 0; off >>= 1) {
    if (threadIdx.x < off) s[threadIdx.x] += s[threadIdx.x + off];
    __syncthreads();
  }
  if (threadIdx.x == 0) bsum[blockIdx.x] = s[0];
}

__global__ __launch_bounds__(256) void k_scan_bsum(int* __restrict__ bsum, int nb) {
  __shared__ int s[256];
  int t = threadIdx.x;
  int v = (t < nb) ? bsum[t] : 0;
  s[t] = v;
  __syncthreads();
  for (int off = 1; off < 256; off <<= 1) {
    int u = (t >= off) ? s[t - off] : 0;
    __syncthreads();
    s[t] += u;
    __syncthreads();
  }
  if (t < nb) bsum[t] = s[t] - v;  // exclusive
}

// emits rp, dinv, and per-copy sub-row offsets subrp[c][i]
__global__ __launch_bounds__(256) void k_scan_final(const int* __restrict__ cnt4, const int* __restrict__ boff,
                                                    int* __restrict__ rp, int* __restrict__ subrp,
                                                    float* __restrict__ dinv, int n) {
  __shared__ int s[256];
  int t = threadIdx.x;
  int i = blockIdx.x * 256 + t;
  int c0 = 0, c1 = 0, c2 = 0, c3 = 0;
  if (i < n) {
    c0 = cnt4[i];
    c1 = cnt4[(size_t)n + i];
    c2 = cnt4[2 * (size_t)n + i];
    c3 = cnt4[3 * (size_t)n + i];
  }
  int v = c0 + c1 + c2 + c3;
  s[t] = v;
  __syncthreads();
  for (int off = 1; off < 256; off <<= 1) {
    int u = (t >= off) ? s[t - off] : 0;
    __syncthreads();
    s[t] += u;
    __syncthreads();
  }
  int excl = s[t] - v + boff[blockIdx.x];
  if (i < n) {
    rp[i] = excl;
    dinv[i] = rsqrtf((float)(v + 1));
    subrp[i] = excl;
    subrp[(size_t)n + i] = excl + c0;
    subrp[2 * (size_t)n + i] = excl + c0 + c1;
    subrp[3 * (size_t)n + i] = excl + c0 + c1 + c2;
  }
  if (i == n - 1) rp[n] = excl + v;
}

__global__ __launch_bounds__(256) void k_scatter(const int* __restrict__ src, const int* __restrict__ dst,
                                                 const int* __restrict__ subrp, int* __restrict__ cursor4,
                                                 int* __restrict__ csr, int E, int n) {
  int e = blockIdx.x * 256 + threadIdx.x;
  if (e < E) {
    int c = e & 3;
    int d = dst[e];
    size_t idx = (size_t)c * n + d;
    int p = subrp[idx] + atomicAdd(&cursor4[idx], 1);
    csr[p] = src[e];
  }
}

// ---------------- weight transpose+convert, all three in one launch ----------------
// W[k][c] f32 -> Wt[c][k] bf16; W3 padded to 48 cols
__global__ __launch_bounds__(256) void k_wt_all(const float* __restrict__ W1, const float* __restrict__ W2,
                                                const float* __restrict__ W3, unsigned short* __restrict__ Wt1,
                                                unsigned short* __restrict__ Wt2, unsigned short* __restrict__ Wt3) {
  int i = blockIdx.x * 256 + threadIdx.x;
  if (i < 16384) {
    int c = i >> 7, k = i & 127;
    Wt1[i] = f2bf(W1[(size_t)k * 128 + c]);
  } else if (i < 32768) {
    int j = i - 16384;
    int c = j >> 7, k = j & 127;
    Wt2[j] = f2bf(W2[(size_t)k * 128 + c]);
  } else if (i < 32768 + 6144) {
    int j = i - 32768;
    int c = j >> 7, k = j & 127;
    Wt3[j] = (c < 40) ? f2bf(W3[(size_t)k * 40 + c]) : (unsigned short)0;
  }
}

// ---------------- MFMA GEMM, fused dinv row-scale, bf16 in/out ----------------
template <int WT_N, int NW_COL, int MOUT>
__global__ __launch_bounds__(256) void k_mfma_gemm(const unsigned short* __restrict__ A,
                                                   const unsigned short* __restrict__ Bt,
                                                   const float* __restrict__ dinv,
                                                   unsigned short* __restrict__ G, int n) {
  constexpr int NW_ROW = 4 / NW_COL;
  int tid = threadIdx.x;
  int wid = tid >> 6, lane = tid & 63;
  int lr = lane & 15, lq = lane >> 4;
  int wrow = wid / NW_COL, wcol = wid % NW_COL;
  int rowBase = blockIdx.x * (NW_ROW * 32) + wrow * 32;
  int colBase = wcol * (WT_N * 16);

  bh8 af[2][4];
#pragma unroll
  for (int rt = 0; rt < 2; rt++) {
    int row = rowBase + rt * 16 + lr;
    const unsigned short* ap = A + (size_t)row * 128 + lq * 8;
    bool ok = row < n;
#pragma unroll
    for (int ks = 0; ks < 4; ks++) {
      bh8 z = {0, 0, 0, 0, 0, 0, 0, 0};
      af[rt][ks] = ok ? *(const bh8*)(ap + ks * 32) : z;
    }
  }
  bh8 bfr[WT_N][4];
#pragma unroll
  for (int ct = 0; ct < WT_N; ct++) {
    const unsigned short* bp = Bt + (size_t)(colBase + ct * 16 + lr) * 128 + lq * 8;
#pragma unroll
    for (int ks = 0; ks < 4; ks++) bfr[ct][ks] = *(const bh8*)(bp + ks * 32);
  }

  f32x4 acc[2][WT_N];
#pragma unroll
  for (int rt = 0; rt < 2; rt++)
#pragma unroll
    for (int ct = 0; ct < WT_N; ct++) acc[rt][ct] = (f32x4){0.f, 0.f, 0.f, 0.f};

#pragma unroll
  for (int ks = 0; ks < 4; ks++)
#pragma unroll
    for (int rt = 0; rt < 2; rt++)
#pragma unroll
      for (int ct = 0; ct < WT_N; ct++)
        acc[rt][ct] = __builtin_amdgcn_mfma_f32_16x16x32_bf16(af[rt][ks], bfr[ct][ks], acc[rt][ct], 0, 0, 0);

  // C/D layout: col=lane&15, row=(lane>>4)*4+reg
#pragma unroll
  for (int rt = 0; rt < 2; rt++)
#pragma unroll
    for (int r = 0; r < 4; r++) {
      int row = rowBase + rt * 16 + lq * 4 + r;
      if (row < n) {
        float di = dinv[row];
#pragma unroll
        for (int ct = 0; ct < WT_N; ct++) {
          int col = colBase + ct * 16 + lr;
          if (MOUT == 128 || col < MOUT)
            G[(size_t)row * MOUT + col] = f2bf(acc[rt][ct][r] * di);
        }
      }
    }
}

// ---------------- aggregation, 128 ch bf16, fused bias+ReLU, bf16 out ----------------
__global__ __launch_bounds__(256) void k_agg_relu128(const unsigned short* __restrict__ g,
                                                     const int* __restrict__ csr, const int* __restrict__ rp,
                                                     const float* __restrict__ dinv, const float* __restrict__ bias,
                                                     unsigned short* __restrict__ out, int n) {
  int t = threadIdx.x;
  int node = blockIdx.x * 8 + (t >> 5);
  if (node >= n) return;
  int c4 = (t & 31) * 4;
  int e0 = rp[node], e1 = rp[node + 1];
  const unsigned short* gp = g + c4;

  float4 a[8];
  {
    uint2 v = *(const uint2*)&gp[(size_t)node * 128];  // self loop
    a[0] = make_float4(bflo(v.x), bfhi(v.x), bflo(v.y), bfhi(v.y));
  }
#pragma unroll
  for (int u = 1; u < 8; u++) a[u] = make_float4(0.f, 0.f, 0.f, 0.f);

  int e = e0;
  for (; e + 8 <= e1; e += 8) {
    int s[8];
#pragma unroll
    for (int u = 0; u < 8; u++) s[u] = csr[e + u];
#pragma unroll
    for (int u = 0; u < 8; u++) {
      uint2 v = *(const uint2*)&gp[(size_t)s[u] * 128];
      a[u].x += bflo(v.x); a[u].y += bfhi(v.x); a[u].z += bflo(v.y); a[u].w += bfhi(v.y);
    }
  }
  for (; e < e1; ++e) {
    int s = csr[e];
    uint2 v = *(const uint2*)&gp[(size_t)s * 128];
    a[0].x += bflo(v.x); a[0].y += bfhi(v.x); a[0].z += bflo(v.y); a[0].w += bfhi(v.y);
  }
#pragma unroll
  for (int u = 4; u < 8; u++) {
    a[u - 4].x += a[u].x; a[u - 4].y += a[u].y; a[u - 4].z += a[u].z; a[u - 4].w += a[u].w;
  }
#pragma unroll
  for (int u = 2; u < 4; u++) {
    a[u - 2].x += a[u].x; a[u - 2].y += a[u].y; a[u - 2].z += a[u].z; a[u - 2].w += a[u].w;
  }
  float4 acc = make_float4(a[0].x + a[1].x, a[0].y + a[1].y, a[0].z + a[1].z, a[0].w + a[1].w);

  float di = dinv[node];
  float4 bb = *(const float4*)&bias[c4];
  uint2 o;
  o.x = pack2(fmaxf(fmaf(di, acc.x, bb.x), 0.f), fmaxf(fmaf(di, acc.y, bb.y), 0.f));
  o.y = pack2(fmaxf(fmaf(di, acc.z, bb.z), 0.f), fmaxf(fmaf(di, acc.w, bb.w), 0.f));
  *(uint2*)&out[(size_t)node * 128 + c4] = o;
}

// ---------------- final aggregation (40 ch bf16) + bias + log_softmax, f32 out ----------------
__global__ __launch_bounds__(256) void k_agg_lsm40(const unsigned short* __restrict__ g,
                                                   const int* __restrict__ csr, const int* __restrict__ rp,
                                                   const float* __restrict__ dinv, const float* __restrict__ bias,
                                                   float* __restrict__ out, int n) {
  int lane = threadIdx.x & 63;
  int node = blockIdx.x * 4 + (threadIdx.x >> 6);
  if (node >= n) return;
  int e0 = rp[node], e1 = rp[node + 1];

  float a[8];
  a[0] = bf1(g[(size_t)node * 40 + lane]);  // self loop (garbage lanes >=40, masked later)
#pragma unroll
  for (int u = 1; u < 8; u++) a[u] = 0.f;

  int e = e0;
  for (; e + 8 <= e1; e += 8) {
    int s[8];
#pragma unroll
    for (int u = 0; u < 8; u++) s[u] = csr[e + u];
#pragma unroll
    for (int u = 0; u < 8; u++) a[u] += bf1(g[(size_t)s[u] * 40 + lane]);
  }
  for (; e < e1; ++e) a[0] += bf1(g[(size_t)csr[e] * 40 + lane]);

  float acc = ((a[0] + a[1]) + (a[2] + a[3])) + ((a[4] + a[5]) + (a[6] + a[7]));

  bool act = lane < 40;
  float v = act ? fmaf(dinv[node], acc, bias[lane]) : -INFINITY;
  float m = v;
#pragma unroll
  for (int off = 32; off > 0; off >>= 1) m = fmaxf(m, __shfl_xor(m, off, 64));
  float ex = act ? __expf(v - m) : 0.f;
  float ssum = ex;
#pragma unroll
  for (int off = 32; off > 0; off >>= 1) ssum += __shfl_xor(ssum, off, 64);
  if (act) out[(size_t)node * 40 + lane] = v - m - __logf(ssum);
}

// ---------------- launch ----------------

extern "C" void kernel_launch(void* const* d_in, const int* in_sizes, int n_in,
                              void* d_out, int out_size, void* d_ws, size_t ws_size,
                              hipStream_t stream) {
  const float* x  = (const float*)d_in[0];
  const int*   ei = (const int*)d_in[1];
  const float* W1 = (const float*)d_in[2];
  const float* b1 = (const float*)d_in[3];
  const float* W2 = (const float*)d_in[4];
  const float* b2 = (const float*)d_in[5];
  const float* W3 = (const float*)d_in[6];
  const float* b3 = (const float*)d_in[7];
  float* out = (float*)d_out;
  int n = in_sizes[0] / 128;
  int E = in_sizes[1] / 2;
  const int* esrc = ei;
  const int* edst = ei + E;

  size_t off = 0;
  auto alloc = [&](size_t bytes) -> void* {
    void* r = (char*)d_ws + off;
    off += (bytes + 255) & ~(size_t)255;
    return r;
  };
  int*   cnt4   = (int*)alloc((size_t)8 * n * 4);  // cnt4[4][n] + cursor4[4][n], one memset
  int*   cursor4 = cnt4 + (size_t)4 * n;
  int*   rp     = (int*)alloc((size_t)(n + 1) * 4);
  int*   subrp  = (int*)alloc((size_t)4 * n * 4);
  int*   bsum   = (int*)alloc(1024);
  float* dinv   = (float*)alloc((size_t)n * 4);
  int*   csr    = (int*)alloc((size_t)E * 4);
  unsigned short* xb   = (unsigned short*)alloc((size_t)n * 128 * 2 + 4096);  // +slack for OOB frag loads
  unsigned short* bufA = (unsigned short*)alloc((size_t)n * 128 * 2 + 4096);
  unsigned short* bufB = (unsigned short*)alloc((size_t)n * 128 * 2 + 4096);
  unsigned short* Wt1  = (unsigned short*)alloc(128 * 128 * 2);
  unsigned short* Wt2  = (unsigned short*)alloc(128 * 128 * 2);
  unsigned short* Wt3  = (unsigned short*)alloc(48 * 128 * 2);

  hipMemsetAsync(cnt4, 0, (size_t)8 * n * 4, stream);

  int ge = (E + 255) / 256;
  int gn = (n + 255) / 256;  // 196 <= 256, single-block scan of block sums is valid
  int t4 = n * 128 / 4;
  k_count_f2b<<<ge, 256, 0, stream>>>(edst, cnt4, x, xb, E, n, t4);
  k_chunk_sum<<<gn, 256, 0, stream>>>(cnt4, bsum, n);
  k_scan_bsum<<<1, 256, 0, stream>>>(bsum, gn);
  k_scan_final<<<gn, 256, 0, stream>>>(cnt4, bsum, rp, subrp, dinv, n);
  k_scatter<<<ge, 256, 0, stream>>>(esrc, edst, subrp, cursor4, csr, E, n);
  k_wt_all<<<(38912 + 255) / 256, 256, 0, stream>>>(W1, W2, W3, Wt1, Wt2, Wt3);

  // layer 1
  k_mfma_gemm<4, 2, 128><<<(n + 63) / 64, 256, 0, stream>>>(xb, Wt1, dinv, bufA, n);
  k_agg_relu128<<<(n + 7) / 8, 256, 0, stream>>>(bufA, csr, rp, dinv, b1, bufB, n);
  // layer 2
  k_mfma_gemm<4, 2, 128><<<(n + 63) / 64, 256, 0, stream>>>(bufB, Wt2, dinv, bufA, n);
  k_agg_relu128<<<(n + 7) / 8, 256, 0, stream>>>(bufA, csr, rp, dinv, b2, bufB, n);
  // layer 3 + log_softmax
  k_mfma_gemm<3, 1, 40><<<(n + 127) / 128, 256, 0, stream>>>(bufB, Wt3, dinv, bufA, n);
  k_agg_lsm40<<<(n + 3) / 4, 256, 0, stream>>>(bufA, csr, rp, dinv, b3, out, n);
}